// Round 11
// baseline (188.869 us; speedup 1.0000x reference)
//
#include <hip/hip_runtime.h>
#include <cstdint>

typedef unsigned short ushort_t;
typedef __attribute__((ext_vector_type(8))) short v8s;
typedef __attribute__((ext_vector_type(4))) short v4s;
typedef __attribute__((ext_vector_type(2))) unsigned v2u;
typedef __attribute__((ext_vector_type(4))) float v4f;

#define MFMA(a, b, c) __builtin_amdgcn_mfma_f32_16x16x32_bf16(a, b, c, 0, 0, 0)
#define QSCALE 0.18033688011112042f   // (1/8) * log2(e): attn softmax runs in exp2 space

// async global->LDS, 16B per lane, dest = wave-uniform base + lane*16
#define GLL(gp, lp) __builtin_amdgcn_global_load_lds(                        \
    (const __attribute__((address_space(1))) void*)(gp),                     \
    (__attribute__((address_space(3))) void*)(lp), 16, 0, 0)

#define WAIT_LGKM0() __builtin_amdgcn_s_waitcnt(0xc07f)   // lgkmcnt(0), vm/exp untouched

__device__ __forceinline__ float bf2f(ushort_t u) {
    union { unsigned u; float f; } x; x.u = ((unsigned)u) << 16; return x.f;
}
__device__ __forceinline__ short f2bf(float f) {
    union { float f; unsigned u; } x; x.f = f;
    unsigned r = x.u + 0x7fffu + ((x.u >> 16) & 1u);   // RNE
    return (short)(r >> 16);
}

// ---------------- fused prep: ONE dispatch for detect + rope + cvt_x + both transposes ----
// regions: [0,2048) cvt_x | [2048,3072) weight transpose | [3072,3328) rope | 3328 flag
// rope table layout [d][t]: cos @ tab[d*2048+t], sin @ tab[65536+d*2048+t]
__global__ __launch_bounds__(256) void prep(const void* __restrict__ xin,
                                            const void* __restrict__ w1,
                                            const void* __restrict__ w2,
                                            ushort_t* __restrict__ xb,
                                            ushort_t* __restrict__ out1,
                                            ushort_t* __restrict__ out2,
                                            int* __restrict__ flag,
                                            float* __restrict__ tab) {
    __shared__ ushort_t tile[64][65];
    __shared__ int cnt;
    int bid = blockIdx.x, tid = threadIdx.x;

    int isbf = 0;
    if (bid < 3072 || bid == 3328) {          // these regions need the dtype flag
        if (tid == 0) cnt = 0;
        __syncthreads();
        unsigned w = ((const unsigned*)xin)[tid];
        int e = (w >> 7) & 0xFF;
        int hit = ((e >= 96 && e <= 135) || (w & 0xFFFFu) == 0) ? 1 : 0;
        atomicAdd(&cnt, hit);
        __syncthreads();
        isbf = (cnt >= 160) ? 1 : 0;
        if (bid == 3328) {
            if (tid == 0) *flag = isbf;
            return;
        }
    }

    if (bid < 2048) {                         // ---- cvt_x: 8 elems/thread ----
        int i = bid * 256 + tid;              // 2048*256 = 524288 = n8
        if (isbf) {
            ((v8s*)xb)[i] = ((const v8s*)xin)[i];
        } else {
            const float* xf = (const float*)xin + (size_t)i * 8;
            v8s o;
            #pragma unroll
            for (int j = 0; j < 8; ++j) o[j] = f2bf(xf[j]);
            ((v8s*)xb)[i] = o;
        }
    } else if (bid < 3072) {                  // ---- weight transpose, 64x64 tiles ----
        int t = bid - 2048;                   // 0..1023
        int bxl = t & 63, by = (t >> 6) * 64;
        const void* in; ushort_t* out; int C, bx;
        if (bxl < 48) { in = w1; out = out1; C = 3072; bx = bxl * 64; }
        else          { in = w2; out = out2; C = 1024; bx = (bxl - 48) * 64; }
        const int R = 1024;
        int tx = tid & 63, ty = tid >> 6;     // (64,4)
        for (int i = ty; i < 64; i += 4) {
            size_t idx = (size_t)(by + i) * C + bx + tx;
            tile[i][tx] = isbf ? ((const ushort_t*)in)[idx]
                               : (ushort_t)f2bf(((const float*)in)[idx]);
        }
        __syncthreads();
        for (int i = ty; i < 64; i += 4) out[(size_t)(bx + i) * R + by + tx] = tile[tx][i];
    } else {                                  // ---- rope table, [d][t] layout ----
        int idx = (bid - 3072) * 256 + tid;   // 65536 = 32*2048
        int d = idx >> 11, t = idx & 2047;    // lanes: consecutive t -> coalesced writes
        float inv_freq = __expf(-(float)d * 0.28782313662425575f);  // 10000^(-d/32)
        float ang = (float)t * inv_freq;
        float sn, cs;
        sincosf(ang, &sn, &cs);
        tab[d * 2048 + t]         = bf2f((ushort_t)f2bf(cs));
        tab[65536 + d * 2048 + t] = bf2f((ushort_t)f2bf(sn));
    }
}

// ---------------- qkv GEMM: C = A * BT^T, 2-phase pipeline, fused RoPE epilogue ----------------
template <int MODE, int BN>
__global__ __launch_bounds__(256) void gemm_bt(const ushort_t* __restrict__ A,
                                               const ushort_t* __restrict__ BT,
                                               void* __restrict__ C,
                                               const int* __restrict__ flagp,
                                               int M, int N, int K,
                                               ushort_t* __restrict__ Qp,
                                               ushort_t* __restrict__ Kp,
                                               ushort_t* __restrict__ Vp,
                                               const float* __restrict__ tab) {
    constexpr int NJ = BN / 32;               // acc cols per wave
    __shared__ __align__(16) ushort_t As[2][128 * 32];
    __shared__ __align__(16) ushort_t Bs[2][BN * 32];
    int tid = threadIdx.x;
    int lane = tid & 63;
    int lr = lane & 15, lc = lane >> 4;
    int w = tid >> 6;
    int wr = (w >> 1) * 64, wc = (w & 1) * (BN / 2);

    // T1: XCD-aware swizzle; nwg % 8 == 0
    int nx = gridDim.x;
    int orig = blockIdx.y * nx + blockIdx.x;
    int cpx = (nx * gridDim.y) >> 3;
    int swz = (orig & 7) * cpx + (orig >> 3);
    int m0 = (swz / nx) * 128, n0 = (swz % nx) * BN;

    int c0 = tid, c1 = tid + 256;
    int r0 = c0 >> 2, s0 = c0 & 3;
    int r1 = c1 >> 2, s1 = c1 & 3;

    const ushort_t* Ag0 = A + (size_t)(m0 + r0) * K + s0 * 8;
    const ushort_t* Ag1 = A + (size_t)(m0 + r1) * K + s1 * 8;
    const ushort_t* Bg0 = BT + (size_t)(n0 + r0) * K + s0 * 8;
    const ushort_t* Bg1 = BT + (size_t)(n0 + r1) * K + s1 * 8;
    const int aoff0 = w * 512;                 // (w*64)*8
    const int aoff1 = 2048 + w * 512;          // (256+w*64)*8
    const int boff0 = w * 512;
    const int boff1 = 2048 + w * 512;

    v4f acc[4][NJ] = {};

    GLL(Ag0, &As[0][aoff0]);
    GLL(Ag1, &As[0][aoff1]);
    GLL(Bg0, &Bs[0][boff0]);
    if constexpr (BN == 128) GLL(Bg1, &Bs[0][boff1]);
    __syncthreads();

    int buf = 0;
    for (int kt = 0; kt < K; kt += 32) {
        if (kt + 32 < K) {
            int nb = buf ^ 1;
            GLL(Ag0 + kt + 32, &As[nb][aoff0]);
            GLL(Ag1 + kt + 32, &As[nb][aoff1]);
            GLL(Bg0 + kt + 32, &Bs[nb][boff0]);
            if constexpr (BN == 128) GLL(Bg1 + kt + 32, &Bs[nb][boff1]);
        }

        v8s af[4], bfr[NJ];
        #pragma unroll
        for (int i = 0; i < 4; ++i)
            af[i] = *(const v8s*)(&As[buf][0] + (wr + i * 16 + lr) * 32 + lc * 8);
        #pragma unroll
        for (int j = 0; j < NJ; ++j)
            bfr[j] = *(const v8s*)(&Bs[buf][0] + (wc + j * 16 + lr) * 32 + lc * 8);
        #pragma unroll
        for (int i = 0; i < 4; ++i)
            #pragma unroll
            for (int j = 0; j < NJ; ++j)
                acc[i][j] = MFMA(af[i], bfr[j], acc[i][j]);

        __syncthreads();
        buf ^= 1;
    }

    if (MODE == 1) {
        int store_f32 = (*flagp == 0);
        #pragma unroll
        for (int i = 0; i < 4; ++i)
            #pragma unroll
            for (int j = 0; j < NJ; ++j)
                #pragma unroll
                for (int r = 0; r < 4; ++r) {
                    int row = m0 + wr + i * 16 + lc * 4 + r;
                    int col = n0 + wc + j * 16 + lr;
                    if (store_f32)
                        ((float*)C)[(size_t)row * N + col] = acc[i][j][r];
                    else
                        ((ushort_t*)C)[(size_t)row * N + col] = (ushort_t)f2bf(acc[i][j][r]);
                }
    } else {  // MODE 2: fused RoPE + reshape epilogue (N=3072 qkv GEMM, BN=128)
        int region = n0 >> 10;                  // 0=Q 1=K 2=V
        int h = ((n0 & 1023) + wc) >> 6;
        if (region < 2) {
            const float sc = (region == 0) ? QSCALE : 1.0f;
            ushort_t* dst = (region == 0) ? Qp : Kp;
            #pragma unroll
            for (int i = 0; i < 4; ++i)
                #pragma unroll
                for (int j = 0; j < 2; ++j) {   // d = j*16+lr in [0,32); partner acc[i][j+2]
                    int d = j * 16 + lr;
                    int tg0 = m0 + wr + i * 16 + lc * 4;
                    int b = tg0 >> 11, tt0 = tg0 & 2047;   // 4 consecutive t, same b
                    v4f cs4 = *(const v4f*)(tab + d * 2048 + tt0);
                    v4f sn4 = *(const v4f*)(tab + 65536 + d * 2048 + tt0);
                    #pragma unroll
                    for (int r = 0; r < 4; ++r) {
                        float x1 = acc[i][j][r], x2 = acc[i][(j + 2) % NJ][r];
                        size_t base = ((size_t)(b * 16 + h) * 2048 + tt0 + r) * 64 + d;
                        dst[base]      = (ushort_t)f2bf((x1 * cs4[r] - x2 * sn4[r]) * sc);
                        dst[base + 32] = (ushort_t)f2bf((x2 * cs4[r] + x1 * sn4[r]) * sc);
                    }
                }
        } else {  // V tiled: Vt[bh][s_tile][d*32 + s_in]
            #pragma unroll
            for (int i = 0; i < 4; ++i)
                #pragma unroll
                for (int j = 0; j < NJ; ++j) {
                    int d = j * 16 + lr;
                    int tg0 = m0 + wr + i * 16 + lc * 4;
                    int b = tg0 >> 11, tt = tg0 & 2047;
                    v4s pk;
                    #pragma unroll
                    for (int r = 0; r < 4; ++r) pk[r] = f2bf(acc[i][j][r]);
                    size_t base = (size_t)(b * 16 + h) * 131072 + (size_t)(tt >> 5) * 2048
                                + (size_t)d * 32 + (tt & 31);
                    *(v4s*)(Vp + base) = pk;
                }
        }
    }
}

// ---------------- out-proj GEMM: 64x64 tiles, 1024 blocks = 4 blocks/CU ----------------
__global__ __launch_bounds__(256, 4) void gemm_o(const ushort_t* __restrict__ A,
                                                 const ushort_t* __restrict__ BT,
                                                 void* __restrict__ C,
                                                 const int* __restrict__ flagp) {
    constexpr int K = 1024, N = 1024;
    __shared__ __align__(16) ushort_t As[2][64 * 64];
    __shared__ __align__(16) ushort_t Bs[2][64 * 64];
    int tid = threadIdx.x;
    int lane = tid & 63;
    int lr = lane & 15, lc = lane >> 4;
    int w = tid >> 6;
    int wr = (w >> 1) * 32, wc = (w & 1) * 32;   // wave tile 32x32

    int nx = gridDim.x;                        // 16
    int orig = blockIdx.y * nx + blockIdx.x;
    int cpx = (nx * gridDim.y) >> 3;           // 128
    int swz = (orig & 7) * cpx + (orig >> 3);
    int m0 = (swz / nx) * 64, n0 = (swz % nx) * 64;

    // staging: A/B 512 chunks each (16B), 2 per thread, source pre-swizzled
    const ushort_t* ag[2]; const ushort_t* bg[2];
    int lof[2];
    #pragma unroll
    for (int q = 0; q < 2; ++q) {
        int c = q * 256 + tid, r = c >> 3, p = c & 7;
        ag[q] = A + (size_t)(m0 + r) * K + ((p ^ (r & 7)) * 8);
        bg[q] = BT + (size_t)(n0 + r) * K + ((p ^ (r & 7)) * 8);
        lof[q] = (q * 256 + w * 64) * 8;       // wave-uniform; HW adds lane*16B
    }

    v4f acc[2][2] = {};

    #pragma unroll
    for (int q = 0; q < 2; ++q) GLL(ag[q], &As[0][lof[q]]);
    #pragma unroll
    for (int q = 0; q < 2; ++q) GLL(bg[q], &Bs[0][lof[q]]);
    __syncthreads();

    int buf = 0;
    for (int t = 0; t < 16; ++t) {
        if (t + 1 < 16) {
            int kg = (t + 1) * 64, nb = buf ^ 1;
            #pragma unroll
            for (int q = 0; q < 2; ++q) GLL(ag[q] + kg, &As[nb][lof[q]]);
            #pragma unroll
            for (int q = 0; q < 2; ++q) GLL(bg[q] + kg, &Bs[nb][lof[q]]);
        }

        v8s af[2][2], bf[2][2];
        #pragma unroll
        for (int i = 0; i < 2; ++i)
            #pragma unroll
            for (int kk = 0; kk < 2; ++kk)
                af[i][kk] = *(const v8s*)(&As[buf][0] + (wr + i * 16 + lr) * 64
                                          + (((kk * 4 + lc) ^ (lr & 7)) * 8));
        #pragma unroll
        for (int j = 0; j < 2; ++j)
            #pragma unroll
            for (int kk = 0; kk < 2; ++kk)
                bf[j][kk] = *(const v8s*)(&Bs[buf][0] + (wc + j * 16 + lr) * 64
                                          + (((kk * 4 + lc) ^ (lr & 7)) * 8));
        __builtin_amdgcn_s_setprio(1);
        #pragma unroll
        for (int i = 0; i < 2; ++i)
            #pragma unroll
            for (int j = 0; j < 2; ++j) {
                acc[i][j] = MFMA(af[i][0], bf[j][0], acc[i][j]);
                acc[i][j] = MFMA(af[i][1], bf[j][1], acc[i][j]);
            }
        __builtin_amdgcn_s_setprio(0);

        __syncthreads();
        buf ^= 1;
    }

    int store_f32 = (*flagp == 0);
    #pragma unroll
    for (int i = 0; i < 2; ++i)
        #pragma unroll
        for (int j = 0; j < 2; ++j)
            #pragma unroll
            for (int r = 0; r < 4; ++r) {
                int row = m0 + wr + i * 16 + lc * 4 + r;
                int col = n0 + wc + j * 16 + lr;
                if (store_f32)
                    ((float*)C)[(size_t)row * N + col] = acc[i][j][r];
                else
                    ((ushort_t*)C)[(size_t)row * N + col] = (ushort_t)f2bf(acc[i][j][r]);
            }
}

// ---------------- flash attention: 8 waves/block, BARRIER-FREE main loop ----------------
// Each wave stages its OWN K tile privately in LDS (4x16B chunks/lane, coalesced global,
// same XOR swizzle, intra-wave in-order LDS write->read). No inter-wave coupling in the
// loop -> zero barriers; the CU scheduler staggers waves so MFMA and VALU phases of
// different waves overlap (fixes the lockstep convoy: MfmaUtil 25 / VALUBusy 30).
// V read direct-from-global (R10). P in registers (R6). One __syncthreads before merge.
__global__ __launch_bounds__(512) void attn(const ushort_t* __restrict__ Qr,
                                            const ushort_t* __restrict__ Kr,
                                            const ushort_t* __restrict__ Vt,
                                            ushort_t* __restrict__ AO) {
    __shared__ __align__(16) char lds[65536];
    int tid = threadIdx.x, lane = tid & 63, W = tid >> 6;
    int lr = lane & 15, lc = lane >> 4;
    int qsub = W & 1, sh = W >> 1;            // sh: s-quarter 0..3
    int L = blockIdx.x;                       // 512 blocks
    int bh = (L & 7) * 4 + ((L >> 3) & 3);    // XCD x owns bh 4x..4x+3 (if %8 maps)
    int qt = L >> 5;                          // 0..15
    int q0 = qt * 128 + qsub * 64;
    int b = bh >> 4, h = bh & 15;
    const ushort_t* Qb = Qr + ((size_t)bh * 2048 + q0) * 64;
    const ushort_t* Kb = Kr + (size_t)bh * 131072 + (size_t)sh * 32768;  // [s][64] quarter
    const ushort_t* Vb = Vt + (size_t)bh * 131072 + (size_t)sh * 32768;  // tiled quarter
    ushort_t* KsW = (ushort_t*)(lds + W * 8192);   // wave-private K dbuf: 2 x 4KB

    // wave-private staging: 4 chunks of 16B per lane = 256 chunks = full 4KB K tile
    const ushort_t* Kg[4];
    int kl[4];
    #pragma unroll
    for (int q = 0; q < 4; ++q) {
        int c = q * 64 + lane, r = c >> 3, pcol = c & 7;
        Kg[q] = Kb + (size_t)r * 64 + pcol * 8;        // + tile*2048
        kl[q] = r * 64 + (pcol ^ (r & 7)) * 8;
    }

    int blr = (lr >> 2) * 8 + (lr & 3);       // permuted kf base row (s-permutation)

    v8s qf[4][2];
    #pragma unroll
    for (int jq = 0; jq < 4; ++jq)
        #pragma unroll
        for (int kk = 0; kk < 2; ++kk)
            qf[jq][kk] = *(const v8s*)(Qb + (size_t)(jq * 16 + lr) * 64 + kk * 32 + lc * 8);

    v4f o[4][4] = {};
    float li[4] = {0.f, 0.f, 0.f, 0.f};

    // preload K tile 0 into buf0; prefetch K tile 1 into regs
    v8s kp[4];
    #pragma unroll
    for (int q = 0; q < 4; ++q) kp[q] = *(const v8s*)(Kg[q]);
    #pragma unroll
    for (int q = 0; q < 4; ++q) *(v8s*)(KsW + kl[q]) = kp[q];
    #pragma unroll
    for (int q = 0; q < 4; ++q) kp[q] = *(const v8s*)(Kg[q] + 2048);

    #pragma unroll 1
    for (int t = 0; t < 16; ++t) {
        int p = t & 1;
        const ushort_t* Kl = KsW + p * 2048;
        const ushort_t* Vg = Vb + (size_t)t * 2048;    // direct-global V fragments

        v8s vf[4];
        #pragma unroll
        for (int i = 0; i < 4; ++i)
            vf[i] = *(const v8s*)(Vg + (i * 16 + lr) * 32 + lc * 8);

        v8s kf[2][2];
        #pragma unroll
        for (int hh = 0; hh < 2; ++hh) {
            int rn = blr + hh * 4;            // rn & 7 == hh*4 + (lr&3)
            int sw = hh * 4 + (lr & 3);
            #pragma unroll
            for (int kk = 0; kk < 2; ++kk)
                kf[hh][kk] = *(const v8s*)(Kl + rn * 64 + (((kk * 4 + lc) ^ sw) * 8));
        }

        v4f St[2][4] = {};
        __builtin_amdgcn_s_setprio(1);
        #pragma unroll
        for (int hh = 0; hh < 2; ++hh)
            #pragma unroll
            for (int jq = 0; jq < 4; ++jq) {
                St[hh][jq] = MFMA(kf[hh][0], qf[jq][0], St[hh][jq]);
                St[hh][jq] = MFMA(kf[hh][1], qf[jq][1], St[hh][jq]);
            }
        __builtin_amdgcn_s_setprio(0);

        // stage K tile t+1 (regs loaded last iteration); prefetch K tile t+2
        if (t + 1 < 16) {
            ushort_t* Kn = KsW + (p ^ 1) * 2048;
            #pragma unroll
            for (int q = 0; q < 4; ++q) *(v8s*)(Kn + kl[q]) = kp[q];
        }
        if (t + 2 < 16) {
            #pragma unroll
            for (int q = 0; q < 4; ++q) kp[q] = *(const v8s*)(Kg[q] + (size_t)(t + 2) * 2048);
        }

        // softmax (exp2 space) + pack P straight into PV B-operand registers
        v8s pf[4];
        #pragma unroll
        for (int jq = 0; jq < 4; ++jq) {
            union { unsigned u[4]; v8s v; } P;
            #pragma unroll
            for (int hh = 0; hh < 2; ++hh) {
                #pragma unroll
                for (int r = 0; r < 4; ++r) {
                    float ev = __builtin_amdgcn_exp2f(St[hh][jq][r]);
                    St[hh][jq][r] = ev;
                    li[jq] += ev;
                }
                P.u[hh * 2 + 0] = __builtin_amdgcn_perm(__float_as_uint(St[hh][jq][1]),
                                                        __float_as_uint(St[hh][jq][0]), 0x07060302u);
                P.u[hh * 2 + 1] = __builtin_amdgcn_perm(__float_as_uint(St[hh][jq][3]),
                                                        __float_as_uint(St[hh][jq][2]), 0x07060302u);
            }
            pf[jq] = P.v;
        }
        __builtin_amdgcn_s_setprio(1);
        #pragma unroll
        for (int jq = 0; jq < 4; ++jq)
            #pragma unroll
            for (int i = 0; i < 4; ++i)
                o[i][jq] = MFMA(vf[i], pf[jq], o[i][jq]);
        __builtin_amdgcn_s_setprio(0);
        // no barrier: staging is wave-private; intra-wave LDS ops are in-order
    }

    // li wave-reduce
    #pragma unroll
    for (int jq = 0; jq < 4; ++jq) {
        li[jq] += __shfl_xor(li[jq], 16);
        li[jq] += __shfl_xor(li[jq], 32);
    }

    // 4-way merge per qsub, sequential (aliases K staging after barrier)
    float* MO = (float*)lds;                  // 3 slots of 64x68 f32 (17408 B each)
    float* Ml = (float*)(lds + 52224);        // 3*64 f32
    __syncthreads();                          // all waves done with private staging
    #pragma unroll 1
    for (int ph = 0; ph < 2; ++ph) {
        if (qsub == ph && sh != 0) {
            float* M = MO + (sh - 1) * 4352;
            #pragma unroll
            for (int jq = 0; jq < 4; ++jq) {
                #pragma unroll
                for (int i = 0; i < 4; ++i)
                    *(v4f*)(M + (jq * 16 + lr) * 68 + i * 16 + lc * 4) = o[i][jq];
                if (lc == 0) Ml[(sh - 1) * 64 + jq * 16 + lr] = li[jq];
            }
        }
        __syncthreads();
        if (qsub == ph && sh == 0) {
            #pragma unroll
            for (int jq = 0; jq < 4; ++jq) {
                int row = jq * 16 + lr;
                float ls = li[jq] + Ml[row] + Ml[64 + row] + Ml[128 + row];
                float inv = 1.0f / ls;
                int tq = q0 + row;
                #pragma unroll
                for (int i = 0; i < 4; ++i) {
                    v4f m0v = *(const v4f*)(MO + row * 68 + i * 16 + lc * 4);
                    v4f m1v = *(const v4f*)(MO + 4352 + row * 68 + i * 16 + lc * 4);
                    v4f m2v = *(const v4f*)(MO + 8704 + row * 68 + i * 16 + lc * 4);
                    v4s pk;
                    #pragma unroll
                    for (int r = 0; r < 4; ++r)
                        pk[r] = f2bf((o[i][jq][r] + m0v[r] + m1v[r] + m2v[r]) * inv);
                    *(v4s*)(AO + (size_t)(b * 2048 + tq) * 1024 + h * 64 + i * 16 + lc * 4) = pk;
                }
            }
        }
        __syncthreads();
    }
}

extern "C" void kernel_launch(void* const* d_in, const int* in_sizes, int n_in,
                              void* d_out, int out_size, void* d_ws, size_t ws_size,
                              hipStream_t stream) {
    char* ws = (char*)d_ws;
    int*      flag  = (int*)ws;                      // 256 B
    ushort_t* wqkvT = (ushort_t*)(ws + 256);         // 6 MB
    ushort_t* woT   = (ushort_t*)(ws + 6291712);     // 2 MB
    ushort_t* xb    = (ushort_t*)(ws + 8388864);     // 8 MB
    ushort_t* Qr    = (ushort_t*)(ws + 16777472);    // 8 MB
    ushort_t* Kr    = (ushort_t*)(ws + 25166080);    // 8 MB
    ushort_t* Vt    = (ushort_t*)(ws + 33554688);    // 8 MB
    ushort_t* AO    = (ushort_t*)(ws + 41943296);    // 8 MB
    float*    tab   = (float*)(ws + 50331904);       // 512 KB

    prep<<<3329, 256, 0, stream>>>(d_in[0], d_in[1], d_in[2], xb, wqkvT, woT, flag, tab);
    gemm_bt<2, 128><<<dim3(24, 32), 256, 0, stream>>>(xb, wqkvT, nullptr, flag, 4096, 3072, 1024,
                                                      Qr, Kr, Vt, tab);
    attn<<<512, 512, 0, stream>>>(Qr, Kr, Vt, AO);
    gemm_o<<<dim3(16, 64), 256, 0, stream>>>(AO, woT, d_out, flag);
}

// Round 12
// 184.058 us; speedup vs baseline: 1.0261x; 1.0261x over previous
//
#include <hip/hip_runtime.h>
#include <cstdint>

typedef unsigned short ushort_t;
typedef __attribute__((ext_vector_type(8))) short v8s;
typedef __attribute__((ext_vector_type(4))) short v4s;
typedef __attribute__((ext_vector_type(2))) unsigned v2u;
typedef __attribute__((ext_vector_type(4))) float v4f;

#define MFMA(a, b, c) __builtin_amdgcn_mfma_f32_16x16x32_bf16(a, b, c, 0, 0, 0)
#define QSCALE 0.18033688011112042f   // (1/8) * log2(e): attn softmax runs in exp2 space

// async global->LDS, 16B per lane, dest = wave-uniform base + lane*16
#define GLL(gp, lp) __builtin_amdgcn_global_load_lds(                        \
    (const __attribute__((address_space(1))) void*)(gp),                     \
    (__attribute__((address_space(3))) void*)(lp), 16, 0, 0)

#define WAIT_LGKM0() __builtin_amdgcn_s_waitcnt(0xc07f)   // lgkmcnt(0), vm/exp untouched

__device__ __forceinline__ float bf2f(ushort_t u) {
    union { unsigned u; float f; } x; x.u = ((unsigned)u) << 16; return x.f;
}
__device__ __forceinline__ short f2bf(float f) {
    union { float f; unsigned u; } x; x.f = f;
    unsigned r = x.u + 0x7fffu + ((x.u >> 16) & 1u);   // RNE
    return (short)(r >> 16);
}

// ---------------- fused prep: ONE dispatch for detect + rope + cvt_x + both transposes ----
// regions: [0,2048) cvt_x | [2048,3072) weight transpose | [3072,3328) rope | 3328 flag
// rope table layout [d][t]: cos @ tab[d*2048+t], sin @ tab[65536+d*2048+t]
__global__ __launch_bounds__(256) void prep(const void* __restrict__ xin,
                                            const void* __restrict__ w1,
                                            const void* __restrict__ w2,
                                            ushort_t* __restrict__ xb,
                                            ushort_t* __restrict__ out1,
                                            ushort_t* __restrict__ out2,
                                            int* __restrict__ flag,
                                            float* __restrict__ tab) {
    __shared__ ushort_t tile[64][65];
    __shared__ int cnt;
    int bid = blockIdx.x, tid = threadIdx.x;

    int isbf = 0;
    if (bid < 3072 || bid == 3328) {          // these regions need the dtype flag
        if (tid == 0) cnt = 0;
        __syncthreads();
        unsigned w = ((const unsigned*)xin)[tid];
        int e = (w >> 7) & 0xFF;
        int hit = ((e >= 96 && e <= 135) || (w & 0xFFFFu) == 0) ? 1 : 0;
        atomicAdd(&cnt, hit);
        __syncthreads();
        isbf = (cnt >= 160) ? 1 : 0;
        if (bid == 3328) {
            if (tid == 0) *flag = isbf;
            return;
        }
    }

    if (bid < 2048) {                         // ---- cvt_x: 8 elems/thread ----
        int i = bid * 256 + tid;              // 2048*256 = 524288 = n8
        if (isbf) {
            ((v8s*)xb)[i] = ((const v8s*)xin)[i];
        } else {
            const float* xf = (const float*)xin + (size_t)i * 8;
            v8s o;
            #pragma unroll
            for (int j = 0; j < 8; ++j) o[j] = f2bf(xf[j]);
            ((v8s*)xb)[i] = o;
        }
    } else if (bid < 3072) {                  // ---- weight transpose, 64x64 tiles ----
        int t = bid - 2048;                   // 0..1023
        int bxl = t & 63, by = (t >> 6) * 64;
        const void* in; ushort_t* out; int C, bx;
        if (bxl < 48) { in = w1; out = out1; C = 3072; bx = bxl * 64; }
        else          { in = w2; out = out2; C = 1024; bx = (bxl - 48) * 64; }
        const int R = 1024;
        int tx = tid & 63, ty = tid >> 6;     // (64,4)
        for (int i = ty; i < 64; i += 4) {
            size_t idx = (size_t)(by + i) * C + bx + tx;
            tile[i][tx] = isbf ? ((const ushort_t*)in)[idx]
                               : (ushort_t)f2bf(((const float*)in)[idx]);
        }
        __syncthreads();
        for (int i = ty; i < 64; i += 4) out[(size_t)(bx + i) * R + by + tx] = tile[tx][i];
    } else {                                  // ---- rope table, [d][t] layout ----
        int idx = (bid - 3072) * 256 + tid;   // 65536 = 32*2048
        int d = idx >> 11, t = idx & 2047;    // lanes: consecutive t -> coalesced writes
        float inv_freq = __expf(-(float)d * 0.28782313662425575f);  // 10000^(-d/32)
        float ang = (float)t * inv_freq;
        float sn, cs;
        sincosf(ang, &sn, &cs);
        tab[d * 2048 + t]         = bf2f((ushort_t)f2bf(cs));
        tab[65536 + d * 2048 + t] = bf2f((ushort_t)f2bf(sn));
    }
}

// ---------------- qkv GEMM: C = A * BT^T, 2-phase pipeline, fused RoPE epilogue ----------------
template <int MODE, int BN>
__global__ __launch_bounds__(256) void gemm_bt(const ushort_t* __restrict__ A,
                                               const ushort_t* __restrict__ BT,
                                               void* __restrict__ C,
                                               const int* __restrict__ flagp,
                                               int M, int N, int K,
                                               ushort_t* __restrict__ Qp,
                                               ushort_t* __restrict__ Kp,
                                               ushort_t* __restrict__ Vp,
                                               const float* __restrict__ tab) {
    constexpr int NJ = BN / 32;               // acc cols per wave
    __shared__ __align__(16) ushort_t As[2][128 * 32];
    __shared__ __align__(16) ushort_t Bs[2][BN * 32];
    int tid = threadIdx.x;
    int lane = tid & 63;
    int lr = lane & 15, lc = lane >> 4;
    int w = tid >> 6;
    int wr = (w >> 1) * 64, wc = (w & 1) * (BN / 2);

    // T1: XCD-aware swizzle; nwg % 8 == 0
    int nx = gridDim.x;
    int orig = blockIdx.y * nx + blockIdx.x;
    int cpx = (nx * gridDim.y) >> 3;
    int swz = (orig & 7) * cpx + (orig >> 3);
    int m0 = (swz / nx) * 128, n0 = (swz % nx) * BN;

    int c0 = tid, c1 = tid + 256;
    int r0 = c0 >> 2, s0 = c0 & 3;
    int r1 = c1 >> 2, s1 = c1 & 3;

    const ushort_t* Ag0 = A + (size_t)(m0 + r0) * K + s0 * 8;
    const ushort_t* Ag1 = A + (size_t)(m0 + r1) * K + s1 * 8;
    const ushort_t* Bg0 = BT + (size_t)(n0 + r0) * K + s0 * 8;
    const ushort_t* Bg1 = BT + (size_t)(n0 + r1) * K + s1 * 8;
    const int aoff0 = w * 512;                 // (w*64)*8
    const int aoff1 = 2048 + w * 512;          // (256+w*64)*8
    const int boff0 = w * 512;
    const int boff1 = 2048 + w * 512;

    v4f acc[4][NJ] = {};

    GLL(Ag0, &As[0][aoff0]);
    GLL(Ag1, &As[0][aoff1]);
    GLL(Bg0, &Bs[0][boff0]);
    if constexpr (BN == 128) GLL(Bg1, &Bs[0][boff1]);
    __syncthreads();

    int buf = 0;
    for (int kt = 0; kt < K; kt += 32) {
        if (kt + 32 < K) {
            int nb = buf ^ 1;
            GLL(Ag0 + kt + 32, &As[nb][aoff0]);
            GLL(Ag1 + kt + 32, &As[nb][aoff1]);
            GLL(Bg0 + kt + 32, &Bs[nb][boff0]);
            if constexpr (BN == 128) GLL(Bg1 + kt + 32, &Bs[nb][boff1]);
        }

        v8s af[4], bfr[NJ];
        #pragma unroll
        for (int i = 0; i < 4; ++i)
            af[i] = *(const v8s*)(&As[buf][0] + (wr + i * 16 + lr) * 32 + lc * 8);
        #pragma unroll
        for (int j = 0; j < NJ; ++j)
            bfr[j] = *(const v8s*)(&Bs[buf][0] + (wc + j * 16 + lr) * 32 + lc * 8);
        #pragma unroll
        for (int i = 0; i < 4; ++i)
            #pragma unroll
            for (int j = 0; j < NJ; ++j)
                acc[i][j] = MFMA(af[i], bfr[j], acc[i][j]);

        __syncthreads();
        buf ^= 1;
    }

    if (MODE == 1) {
        int store_f32 = (*flagp == 0);
        #pragma unroll
        for (int i = 0; i < 4; ++i)
            #pragma unroll
            for (int j = 0; j < NJ; ++j)
                #pragma unroll
                for (int r = 0; r < 4; ++r) {
                    int row = m0 + wr + i * 16 + lc * 4 + r;
                    int col = n0 + wc + j * 16 + lr;
                    if (store_f32)
                        ((float*)C)[(size_t)row * N + col] = acc[i][j][r];
                    else
                        ((ushort_t*)C)[(size_t)row * N + col] = (ushort_t)f2bf(acc[i][j][r]);
                }
    } else {  // MODE 2: fused RoPE + reshape epilogue (N=3072 qkv GEMM, BN=128)
        int region = n0 >> 10;                  // 0=Q 1=K 2=V
        int h = ((n0 & 1023) + wc) >> 6;
        if (region < 2) {
            const float sc = (region == 0) ? QSCALE : 1.0f;
            ushort_t* dst = (region == 0) ? Qp : Kp;
            #pragma unroll
            for (int i = 0; i < 4; ++i)
                #pragma unroll
                for (int j = 0; j < 2; ++j) {   // d = j*16+lr in [0,32); partner acc[i][j+2]
                    int d = j * 16 + lr;
                    int tg0 = m0 + wr + i * 16 + lc * 4;
                    int b = tg0 >> 11, tt0 = tg0 & 2047;   // 4 consecutive t, same b
                    v4f cs4 = *(const v4f*)(tab + d * 2048 + tt0);
                    v4f sn4 = *(const v4f*)(tab + 65536 + d * 2048 + tt0);
                    #pragma unroll
                    for (int r = 0; r < 4; ++r) {
                        float x1 = acc[i][j][r], x2 = acc[i][(j + 2) % NJ][r];
                        size_t base = ((size_t)(b * 16 + h) * 2048 + tt0 + r) * 64 + d;
                        dst[base]      = (ushort_t)f2bf((x1 * cs4[r] - x2 * sn4[r]) * sc);
                        dst[base + 32] = (ushort_t)f2bf((x2 * cs4[r] + x1 * sn4[r]) * sc);
                    }
                }
        } else {  // V tiled: Vt[bh][s_tile][d*32 + s_in]
            #pragma unroll
            for (int i = 0; i < 4; ++i)
                #pragma unroll
                for (int j = 0; j < NJ; ++j) {
                    int d = j * 16 + lr;
                    int tg0 = m0 + wr + i * 16 + lc * 4;
                    int b = tg0 >> 11, tt = tg0 & 2047;
                    v4s pk;
                    #pragma unroll
                    for (int r = 0; r < 4; ++r) pk[r] = f2bf(acc[i][j][r]);
                    size_t base = (size_t)(b * 16 + h) * 131072 + (size_t)(tt >> 5) * 2048
                                + (size_t)d * 32 + (tt & 31);
                    *(v4s*)(Vp + base) = pk;
                }
        }
    }
}

// ---------------- out-proj GEMM: 64x64 tiles, 1024 blocks = 4 blocks/CU ----------------
__global__ __launch_bounds__(256, 4) void gemm_o(const ushort_t* __restrict__ A,
                                                 const ushort_t* __restrict__ BT,
                                                 void* __restrict__ C,
                                                 const int* __restrict__ flagp) {
    constexpr int K = 1024, N = 1024;
    __shared__ __align__(16) ushort_t As[2][64 * 64];
    __shared__ __align__(16) ushort_t Bs[2][64 * 64];
    int tid = threadIdx.x;
    int lane = tid & 63;
    int lr = lane & 15, lc = lane >> 4;
    int w = tid >> 6;
    int wr = (w >> 1) * 32, wc = (w & 1) * 32;   // wave tile 32x32

    int nx = gridDim.x;                        // 16
    int orig = blockIdx.y * nx + blockIdx.x;
    int cpx = (nx * gridDim.y) >> 3;           // 128
    int swz = (orig & 7) * cpx + (orig >> 3);
    int m0 = (swz / nx) * 64, n0 = (swz % nx) * 64;

    // staging: A/B 512 chunks each (16B), 2 per thread, source pre-swizzled
    const ushort_t* ag[2]; const ushort_t* bg[2];
    int lof[2];
    #pragma unroll
    for (int q = 0; q < 2; ++q) {
        int c = q * 256 + tid, r = c >> 3, p = c & 7;
        ag[q] = A + (size_t)(m0 + r) * K + ((p ^ (r & 7)) * 8);
        bg[q] = BT + (size_t)(n0 + r) * K + ((p ^ (r & 7)) * 8);
        lof[q] = (q * 256 + w * 64) * 8;       // wave-uniform; HW adds lane*16B
    }

    v4f acc[2][2] = {};

    #pragma unroll
    for (int q = 0; q < 2; ++q) GLL(ag[q], &As[0][lof[q]]);
    #pragma unroll
    for (int q = 0; q < 2; ++q) GLL(bg[q], &Bs[0][lof[q]]);
    __syncthreads();

    int buf = 0;
    for (int t = 0; t < 16; ++t) {
        if (t + 1 < 16) {
            int kg = (t + 1) * 64, nb = buf ^ 1;
            #pragma unroll
            for (int q = 0; q < 2; ++q) GLL(ag[q] + kg, &As[nb][lof[q]]);
            #pragma unroll
            for (int q = 0; q < 2; ++q) GLL(bg[q] + kg, &Bs[nb][lof[q]]);
        }

        v8s af[2][2], bf[2][2];
        #pragma unroll
        for (int i = 0; i < 2; ++i)
            #pragma unroll
            for (int kk = 0; kk < 2; ++kk)
                af[i][kk] = *(const v8s*)(&As[buf][0] + (wr + i * 16 + lr) * 64
                                          + (((kk * 4 + lc) ^ (lr & 7)) * 8));
        #pragma unroll
        for (int j = 0; j < 2; ++j)
            #pragma unroll
            for (int kk = 0; kk < 2; ++kk)
                bf[j][kk] = *(const v8s*)(&Bs[buf][0] + (wc + j * 16 + lr) * 64
                                          + (((kk * 4 + lc) ^ (lr & 7)) * 8));
        __builtin_amdgcn_s_setprio(1);
        #pragma unroll
        for (int i = 0; i < 2; ++i)
            #pragma unroll
            for (int j = 0; j < 2; ++j) {
                acc[i][j] = MFMA(af[i][0], bf[j][0], acc[i][j]);
                acc[i][j] = MFMA(af[i][1], bf[j][1], acc[i][j]);
            }
        __builtin_amdgcn_s_setprio(0);

        __syncthreads();
        buf ^= 1;
    }

    int store_f32 = (*flagp == 0);
    #pragma unroll
    for (int i = 0; i < 2; ++i)
        #pragma unroll
        for (int j = 0; j < 2; ++j)
            #pragma unroll
            for (int r = 0; r < 4; ++r) {
                int row = m0 + wr + i * 16 + lc * 4 + r;
                int col = n0 + wc + j * 16 + lr;
                if (store_f32)
                    ((float*)C)[(size_t)row * N + col] = acc[i][j][r];
                else
                    ((ushort_t*)C)[(size_t)row * N + col] = (ushort_t)f2bf(acc[i][j][r]);
            }
}

// ---------------- flash attention: 8 waves/block, barrier-free, per-jq pipelined chains ----
// R12: tile body restructured into 4 independent jq-chains {QK(8 MFMA) -> exp2/pack -> PV}
// so the scheduler overlaps jq_k's softmax (VALU/trans) with jq_{k+1}'s QK (matrix pipe)
// WITHIN a wave -- R11 proved inter-wave overlap alone leaves 50% dependency stall.
// li computed on the MFMA pipe: oL[jq] = MFMA(ones, pf) accumulates sum_s P[s][q] in every
// reg (row-sum broadcast) -> deletes 32 VALU adds/tile AND the final shfl reduce.
// Wave-private K staging (R11), V direct-from-global (R10), P in registers (R6).
__global__ __launch_bounds__(512) void attn(const ushort_t* __restrict__ Qr,
                                            const ushort_t* __restrict__ Kr,
                                            const ushort_t* __restrict__ Vt,
                                            ushort_t* __restrict__ AO) {
    __shared__ __align__(16) char lds[65536];
    int tid = threadIdx.x, lane = tid & 63, W = tid >> 6;
    int lr = lane & 15, lc = lane >> 4;
    int qsub = W & 1, sh = W >> 1;            // sh: s-quarter 0..3
    int L = blockIdx.x;                       // 512 blocks
    int bh = (L & 7) * 4 + ((L >> 3) & 3);    // XCD x owns bh 4x..4x+3 (if %8 maps)
    int qt = L >> 5;                          // 0..15
    int q0 = qt * 128 + qsub * 64;
    int b = bh >> 4, h = bh & 15;
    const ushort_t* Qb = Qr + ((size_t)bh * 2048 + q0) * 64;
    const ushort_t* Kb = Kr + (size_t)bh * 131072 + (size_t)sh * 32768;  // [s][64] quarter
    const ushort_t* Vb = Vt + (size_t)bh * 131072 + (size_t)sh * 32768;  // tiled quarter
    ushort_t* KsW = (ushort_t*)(lds + W * 8192);   // wave-private K dbuf: 2 x 4KB

    // wave-private staging: 4 chunks of 16B per lane = 256 chunks = full 4KB K tile
    const ushort_t* Kg[4];
    int kl[4];
    #pragma unroll
    for (int q = 0; q < 4; ++q) {
        int c = q * 64 + lane, r = c >> 3, pcol = c & 7;
        Kg[q] = Kb + (size_t)r * 64 + pcol * 8;        // + tile*2048
        kl[q] = r * 64 + (pcol ^ (r & 7)) * 8;
    }

    int blr = (lr >> 2) * 8 + (lr & 3);       // permuted kf base row (s-permutation)

    v8s ones;                                  // bf16 1.0 x8 (A-operand for li row-sum MFMA)
    #pragma unroll
    for (int e = 0; e < 8; ++e) ones[e] = (short)0x3F80;

    v8s qf[4][2];
    #pragma unroll
    for (int jq = 0; jq < 4; ++jq)
        #pragma unroll
        for (int kk = 0; kk < 2; ++kk)
            qf[jq][kk] = *(const v8s*)(Qb + (size_t)(jq * 16 + lr) * 64 + kk * 32 + lc * 8);

    v4f o[4][4] = {};
    v4f oL[4] = {};                            // li accumulators (row-sum via ones-MFMA)

    // preload K tile 0 into buf0; prefetch K tile 1 into regs
    v8s kp[4];
    #pragma unroll
    for (int q = 0; q < 4; ++q) kp[q] = *(const v8s*)(Kg[q]);
    #pragma unroll
    for (int q = 0; q < 4; ++q) *(v8s*)(KsW + kl[q]) = kp[q];
    #pragma unroll
    for (int q = 0; q < 4; ++q) kp[q] = *(const v8s*)(Kg[q] + 2048);

    #pragma unroll 1
    for (int t = 0; t < 16; ++t) {
        int p = t & 1;
        const ushort_t* Kl = KsW + p * 2048;
        const ushort_t* Vg = Vb + (size_t)t * 2048;    // direct-global V fragments

        v8s vf[4];
        #pragma unroll
        for (int i = 0; i < 4; ++i)
            vf[i] = *(const v8s*)(Vg + (i * 16 + lr) * 32 + lc * 8);

        v8s kf[2][2];
        #pragma unroll
        for (int hh = 0; hh < 2; ++hh) {
            int rn = blr + hh * 4;            // rn & 7 == hh*4 + (lr&3)
            int sw = hh * 4 + (lr & 3);
            #pragma unroll
            for (int kk = 0; kk < 2; ++kk)
                kf[hh][kk] = *(const v8s*)(Kl + rn * 64 + (((kk * 4 + lc) ^ sw) * 8));
        }

        // stage K tile t+1 early (no dependents until next tile); prefetch t+2
        if (t + 1 < 16) {
            ushort_t* Kn = KsW + (p ^ 1) * 2048;
            #pragma unroll
            for (int q = 0; q < 4; ++q) *(v8s*)(Kn + kl[q]) = kp[q];
        }
        if (t + 2 < 16) {
            #pragma unroll
            for (int q = 0; q < 4; ++q) kp[q] = *(const v8s*)(Kg[q] + (size_t)(t + 2) * 2048);
        }

        // 4 independent jq-chains: QK -> exp2/pack -> PV (+ li on MFMA pipe)
        #pragma unroll
        for (int jq = 0; jq < 4; ++jq) {
            v4f St[2] = {};
            #pragma unroll
            for (int hh = 0; hh < 2; ++hh) {
                St[hh] = MFMA(kf[hh][0], qf[jq][0], St[hh]);
                St[hh] = MFMA(kf[hh][1], qf[jq][1], St[hh]);
            }
            union { unsigned u[4]; v8s v; } P;
            #pragma unroll
            for (int hh = 0; hh < 2; ++hh) {
                #pragma unroll
                for (int r = 0; r < 4; ++r)
                    St[hh][r] = __builtin_amdgcn_exp2f(St[hh][r]);
                P.u[hh * 2 + 0] = __builtin_amdgcn_perm(__float_as_uint(St[hh][1]),
                                                        __float_as_uint(St[hh][0]), 0x07060302u);
                P.u[hh * 2 + 1] = __builtin_amdgcn_perm(__float_as_uint(St[hh][3]),
                                                        __float_as_uint(St[hh][2]), 0x07060302u);
            }
            v8s pf = P.v;
            oL[jq] = MFMA(ones, pf, oL[jq]);   // li: sum_s P[s][q=lr], broadcast to all regs
            #pragma unroll
            for (int i = 0; i < 4; ++i)
                o[i][jq] = MFMA(vf[i], pf, o[i][jq]);
        }
        // no barrier: staging is wave-private; intra-wave LDS ops are in-order
    }

    // li: every lane/reg of oL[jq] holds the full row-sum for q-row (jq*16+lr)
    float li[4];
    #pragma unroll
    for (int jq = 0; jq < 4; ++jq) li[jq] = oL[jq][0];

    // 4-way merge per qsub, sequential (aliases K staging after barrier)
    float* MO = (float*)lds;                  // 3 slots of 64x68 f32 (17408 B each)
    float* Ml = (float*)(lds + 52224);        // 3*64 f32
    __syncthreads();                          // all waves done with private staging
    #pragma unroll 1
    for (int ph = 0; ph < 2; ++ph) {
        if (qsub == ph && sh != 0) {
            float* M = MO + (sh - 1) * 4352;
            #pragma unroll
            for (int jq = 0; jq < 4; ++jq) {
                #pragma unroll
                for (int i = 0; i < 4; ++i)
                    *(v4f*)(M + (jq * 16 + lr) * 68 + i * 16 + lc * 4) = o[i][jq];
                if (lc == 0) Ml[(sh - 1) * 64 + jq * 16 + lr] = li[jq];
            }
        }
        __syncthreads();
        if (qsub == ph && sh == 0) {
            #pragma unroll
            for (int jq = 0; jq < 4; ++jq) {
                int row = jq * 16 + lr;
                float ls = li[jq] + Ml[row] + Ml[64 + row] + Ml[128 + row];
                float inv = 1.0f / ls;
                int tq = q0 + row;
                #pragma unroll
                for (int i = 0; i < 4; ++i) {
                    v4f m0v = *(const v4f*)(MO + row * 68 + i * 16 + lc * 4);
                    v4f m1v = *(const v4f*)(MO + 4352 + row * 68 + i * 16 + lc * 4);
                    v4f m2v = *(const v4f*)(MO + 8704 + row * 68 + i * 16 + lc * 4);
                    v4s pk;
                    #pragma unroll
                    for (int r = 0; r < 4; ++r)
                        pk[r] = f2bf((o[i][jq][r] + m0v[r] + m1v[r] + m2v[r]) * inv);
                    *(v4s*)(AO + (size_t)(b * 2048 + tq) * 1024 + h * 64 + i * 16 + lc * 4) = pk;
                }
            }
        }
        __syncthreads();
    }
}

extern "C" void kernel_launch(void* const* d_in, const int* in_sizes, int n_in,
                              void* d_out, int out_size, void* d_ws, size_t ws_size,
                              hipStream_t stream) {
    char* ws = (char*)d_ws;
    int*      flag  = (int*)ws;                      // 256 B
    ushort_t* wqkvT = (ushort_t*)(ws + 256);         // 6 MB
    ushort_t* woT   = (ushort_t*)(ws + 6291712);     // 2 MB
    ushort_t* xb    = (ushort_t*)(ws + 8388864);     // 8 MB
    ushort_t* Qr    = (ushort_t*)(ws + 16777472);    // 8 MB
    ushort_t* Kr    = (ushort_t*)(ws + 25166080);    // 8 MB
    ushort_t* Vt    = (ushort_t*)(ws + 33554688);    // 8 MB
    ushort_t* AO    = (ushort_t*)(ws + 41943296);    // 8 MB
    float*    tab   = (float*)(ws + 50331904);       // 512 KB

    prep<<<3329, 256, 0, stream>>>(d_in[0], d_in[1], d_in[2], xb, wqkvT, woT, flag, tab);
    gemm_bt<2, 128><<<dim3(24, 32), 256, 0, stream>>>(xb, wqkvT, nullptr, flag, 4096, 3072, 1024,
                                                      Qr, Kr, Vt, tab);
    attn<<<512, 512, 0, stream>>>(Qr, Kr, Vt, AO);
    gemm_o<<<dim3(16, 64), 256, 0, stream>>>(AO, woT, d_out, flag);
}